// Round 12
// baseline (258.650 us; speedup 1.0000x reference)
//
#include <hip/hip_runtime.h>

#define RAW 256
#define LAT 100
#define LAT2 200
#define NCLS 55
#define FDIM 64    // padded row: 0..54 classes, 55 ones-col, 56..63 zero (fp16 row = 128 B)
#define GR 32      // rows per gemm block (fp32 LDS tile = 32 KB; r4/r8/r9/r11 measured ~101 us)
#define CAP 64     // padded-CSR capacity per node (front = src<N/2, back = src>=N/2)

typedef _Float16 h8 __attribute__((ext_vector_type(8)));

// ---- wave-per-row small-GEMM helpers (lane j = output col, 64-wide padded B) ----
__device__ __forceinline__ float dotrow(const float* __restrict__ Arow,
                                        const float* __restrict__ Bp, int K, int j) {
  float a0 = 0.f, a1 = 0.f, a2 = 0.f, a3 = 0.f;
  int k = 0;
  for (; k + 3 < K; k += 4) {
    a0 += Arow[k + 0] * Bp[(k + 0) * 64 + j];
    a1 += Arow[k + 1] * Bp[(k + 1) * 64 + j];
    a2 += Arow[k + 2] * Bp[(k + 2) * 64 + j];
    a3 += Arow[k + 3] * Bp[(k + 3) * 64 + j];
  }
  for (; k < K; ++k) a0 += Arow[k] * Bp[k * 64 + j];
  return (a0 + a1) + (a2 + a3);
}

__device__ __forceinline__ float dotrow_wc(const float* __restrict__ Arow,
                                           const float* __restrict__ Wc, int K, int j) {
  if (j >= NCLS) return 0.f;
  float a0 = 0.f, a1 = 0.f, a2 = 0.f, a3 = 0.f;
  for (int k = 0; k + 3 < K; k += 4) {
    a0 += Arow[k + 0] * Wc[(k + 0) * NCLS + j];
    a1 += Arow[k + 1] * Wc[(k + 1) * NCLS + j];
    a2 += Arow[k + 2] * Wc[(k + 2) * NCLS + j];
    a3 += Arow[k + 3] * Wc[(k + 3) * NCLS + j];
  }
  return (a0 + a1) + (a2 + a3);
}

// ---------------- s1: [zero deg/fill + dummy rows][P = W_ext@W1][Qp = W2@Wc, c0][r = b_ext@W1] ----------------
__global__ __launch_bounds__(256) void s1_kernel(
    int4* __restrict__ zbase, int zcount16,
    _Float16* __restrict__ Ydummy, _Float16* __restrict__ Bdummy,
    const float* __restrict__ W_ext, const float* __restrict__ W1,
    const float* __restrict__ b_ext,
    const float* __restrict__ W2, const float* __restrict__ b2,
    const float* __restrict__ Wc,
    float* __restrict__ P, float* __restrict__ Qp,
    float* __restrict__ rvec, float* __restrict__ cvec, int nZ) {
  int b = blockIdx.x, t = threadIdx.x;
  if (b < nZ) {
    int idx = b * 256 + t;
    if (idx < zcount16) zbase[idx] = make_int4(0, 0, 0, 0);
    if (b == 0) {
      if (t < 8) ((int4*)Ydummy)[t] = make_int4(0, 0, 0, 0);
      else if (t < 16) ((int4*)Bdummy)[t - 8] = make_int4(0, 0, 0, 0);
    }
    return;
  }
  b -= nZ;
  if (b < 128) {  // P rows: 2 rows/block, 128 lanes/row
    int row = b * 2 + (t >> 7);
    int col = t & 127;
    if (col < LAT) {
      const float* a = &W_ext[row * LAT];
      float s0 = 0.f, s1 = 0.f, s2 = 0.f, s3 = 0.f;
      for (int k = 0; k < LAT; k += 4) {
        s0 += a[k + 0] * W1[(k + 0) * LAT + col];
        s1 += a[k + 1] * W1[(k + 1) * LAT + col];
        s2 += a[k + 2] * W1[(k + 2) * LAT + col];
        s3 += a[k + 3] * W1[(k + 3) * LAT + col];
      }
      P[row * LAT + col] = (s0 + s1) + (s2 + s3);
    }
    return;
  }
  b -= 128;
  if (b < 26) {  // Q rows + c0
    int task = b * 4 + (t >> 6);
    int j = t & 63;
    if (task < LAT)
      Qp[task * 64 + j] = dotrow_wc(&W2[task * LAT2], Wc, LAT2, j);
    else if (task == LAT)
      cvec[128 + j] = dotrow_wc(b2, Wc, LAT2, j);  // c0
    return;
  }
  // r = b_ext @ W1
  if (t < LAT) {
    float s0 = 0.f, s1 = 0.f, s2 = 0.f, s3 = 0.f;
    for (int k = 0; k < LAT; k += 4) {
      s0 += b_ext[k + 0] * W1[(k + 0) * LAT + t];
      s1 += b_ext[k + 1] * W1[(k + 1) * LAT + t];
      s2 += b_ext[k + 2] * W1[(k + 2) * LAT + t];
      s3 += b_ext[k + 3] * W1[(k + 3) * LAT + t];
    }
    rvec[t] = (s0 + s1) + (s2 + s3);
  }
}

// ---------------- s2: Wall = P@Qp, c2 = r@Qp, c1 = b1@Qp ----------------
__global__ __launch_bounds__(256) void s2_kernel(
    const float* __restrict__ P, const float* __restrict__ Qp,
    const float* __restrict__ rvec, const float* __restrict__ b1,
    float* __restrict__ Wallp, float* __restrict__ cvec) {
  int task = blockIdx.x * 4 + (threadIdx.x >> 6);
  int j = threadIdx.x & 63;
  if (task < RAW)
    Wallp[task * 64 + j] = dotrow(&P[task * LAT], Qp, LAT, j);
  else if (task == RAW)
    cvec[j] = dotrow(rvec, Qp, LAT, j);       // c2
  else if (task == RAW + 1)
    cvec[64 + j] = dotrow(b1, Qp, LAT, j);    // c1
}

// ---------------- mega: edge blocks (split-cursor CSR + out-deg atomics) ∥ gemm blocks ----------------
__global__ __launch_bounds__(256) void mega(
    const int* __restrict__ src, const int* __restrict__ dst,
    int* deg_o, int* fill_lo, int* fill_hi, unsigned short* csr_pad, int E,
    const float* __restrict__ X, const float* __restrict__ Wallp,
    _Float16* __restrict__ Y, int N, int nE, int nGm) {
  __shared__ float Xs[GR][RAW];  // 32 KB
  int b = blockIdx.x;
  int t = threadIdx.x;
  int total = nE + nGm;
  long long lo = (long long)b * nGm / total;
  long long hi = (long long)(b + 1) * nGm / total;
  if (hi == lo) {
    // ---- edge block ----
    int e = (b - (int)lo) * 256 + t;
    if (e < E) {
      int s = src[e];
      int d = dst[e];
      int half = N >> 1;
      if (s < half) {
        int cur = atomicAdd(&fill_lo[d], 1);
        if (cur < CAP) csr_pad[(size_t)d * CAP + cur] = (unsigned short)s;
      } else {
        int cur = atomicAdd(&fill_hi[d], 1);
        int pos = CAP - 1 - cur;
        if (pos >= 0) csr_pad[(size_t)d * CAP + pos] = (unsigned short)s;
      }
      atomicAdd(&deg_o[s], 1);
    }
    return;
  }
  // ---- gemm block ----
  int r0 = (int)lo * GR;
#pragma unroll
  for (int i = 0; i < 8; ++i) {
    int f = t + 256 * i;
    int rr = f >> 6;
    int kp = (f & 63) << 2;
    int row = r0 + rr;
    float4 v = make_float4(0.f, 0.f, 0.f, 0.f);
    if (row < N) v = *(const float4*)&X[(size_t)row * RAW + kp];
    *(float4*)&Xs[rr][kp] = v;
  }
  __syncthreads();
  int j = t & 63;
  int rg = t >> 6;
  float acc[8];
#pragma unroll
  for (int i = 0; i < 8; ++i) acc[i] = 0.f;
  for (int k = 0; k < RAW; k += 4) {
    float w0 = Wallp[(k + 0) * 64 + j];
    float w1 = Wallp[(k + 1) * 64 + j];
    float w2 = Wallp[(k + 2) * 64 + j];
    float w3 = Wallp[(k + 3) * 64 + j];
#pragma unroll
    for (int i = 0; i < 8; ++i) {
      float4 x = *(const float4*)&Xs[rg * 8 + i][k];
      acc[i] += x.x * w0 + x.y * w1 + x.z * w2 + x.w * w3;
    }
  }
#pragma unroll
  for (int i = 0; i < 8; ++i) {
    int row = r0 + rg * 8 + i;
    if (row < N) {
      float val = (j < NCLS) ? acc[i] : ((j == NCLS) ? 1.f : 0.f);
      Y[(size_t)row * FDIM + j] = (_Float16)val;
    }
  }
}

// ---------------- agg1: merged masked gather; B = s_mid(n)·Σ inv_o(s)·Y[s]; u from ones-col ----------------
// Slot indices masked to dummy row N (zeroed) with ?: BEFORE the gather -> no csr_init needed.
__global__ __launch_bounds__(256) void agg1_kernel(const _Float16* __restrict__ Y,
    const unsigned short* __restrict__ csr_pad,
    const int* __restrict__ fill_lo, const int* __restrict__ fill_hi,
    const int* __restrict__ deg_o,
    _Float16* __restrict__ B, float* __restrict__ u_out, int N) {
  int n = blockIdx.x * 32 + (threadIdx.x >> 3);
  int l = threadIdx.x & 7;
  if (n >= N) return;
  int flo = min(fill_lo[n], CAP);
  int fhi = min(fill_hi[n], CAP);
  int fi = fill_lo[n] + fill_hi[n];
  const unsigned short* lst = &csr_pad[(size_t)n * CAP];
  float A[8];
#pragma unroll
  for (int q = 0; q < 8; ++q) A[q] = 0.f;
  int mx = flo > fhi ? flo : fhi;
  int nIt = (mx + 3) >> 2;
  for (int it = 0; it < nIt; ++it) {
    int f0 = it * 4;
    int s[4], tt[4];
#pragma unroll
    for (int i = 0; i < 4; ++i) {
      int fx = f0 + i;
      s[i]  = (fx < flo) ? (int)lst[fx] : N;            // dummy zero row when past end
      tt[i] = (fx < fhi) ? (int)lst[CAP - 1 - fx] : N;
    }
    float ws[4], wt[4];
#pragma unroll
    for (int i = 0; i < 4; ++i) {
      ws[i] = 1.f / sqrtf(fmaxf((float)deg_o[s[i]], 1.f));   // deg_o[N]=0 -> w=1, row=0
      wt[i] = 1.f / sqrtf(fmaxf((float)deg_o[tt[i]], 1.f));
    }
    h8 v0 = *(const h8*)&Y[(size_t)s[0] * FDIM + 8 * l];
    h8 v1 = *(const h8*)&Y[(size_t)s[1] * FDIM + 8 * l];
    h8 v2 = *(const h8*)&Y[(size_t)s[2] * FDIM + 8 * l];
    h8 v3 = *(const h8*)&Y[(size_t)s[3] * FDIM + 8 * l];
    h8 u0 = *(const h8*)&Y[(size_t)tt[0] * FDIM + 8 * l];
    h8 u1 = *(const h8*)&Y[(size_t)tt[1] * FDIM + 8 * l];
    h8 u2 = *(const h8*)&Y[(size_t)tt[2] * FDIM + 8 * l];
    h8 u3 = *(const h8*)&Y[(size_t)tt[3] * FDIM + 8 * l];
#pragma unroll
    for (int q = 0; q < 8; ++q) {
      A[q] += (ws[0] * (float)v0[q] + ws[1] * (float)v1[q])
            + (ws[2] * (float)v2[q] + ws[3] * (float)v3[q])
            + (wt[0] * (float)u0[q] + wt[1] * (float)u1[q])
            + (wt[2] * (float)u2[q] + wt[3] * (float)u3[q]);
    }
  }
  float inv_i = 1.f / sqrtf(fmaxf((float)fi, 1.f));
  float inv_on = 1.f / sqrtf(fmaxf((float)deg_o[n], 1.f));
  float sm = inv_i * inv_on;                 // next layer's inv_o pre-applied
  h8 o;
#pragma unroll
  for (int q = 0; q < 8; ++q) o[q] = (_Float16)(A[q] * sm);
  *(h8*)&B[(size_t)n * FDIM + 8 * l] = o;
  if (l == 6) u_out[n] = A[7] * inv_i;       // col 55
}

// ---------------- agg2: merged masked gather; bufA fp32 = inv_i(n)·Σ B[s] ----------------
__global__ __launch_bounds__(256) void agg2_kernel(const _Float16* __restrict__ Bm,
    const unsigned short* __restrict__ csr_pad,
    const int* __restrict__ fill_lo, const int* __restrict__ fill_hi,
    float* __restrict__ bufA, int N) {
  int n = blockIdx.x * 32 + (threadIdx.x >> 3);
  int l = threadIdx.x & 7;
  if (n >= N) return;
  int flo = min(fill_lo[n], CAP);
  int fhi = min(fill_hi[n], CAP);
  int fi = fill_lo[n] + fill_hi[n];
  const unsigned short* lst = &csr_pad[(size_t)n * CAP];
  float A[8];
#pragma unroll
  for (int q = 0; q < 8; ++q) A[q] = 0.f;
  int mx = flo > fhi ? flo : fhi;
  int nIt = (mx + 3) >> 2;
  for (int it = 0; it < nIt; ++it) {
    int f0 = it * 4;
    int s[4], tt[4];
#pragma unroll
    for (int i = 0; i < 4; ++i) {
      int fx = f0 + i;
      s[i]  = (fx < flo) ? (int)lst[fx] : N;
      tt[i] = (fx < fhi) ? (int)lst[CAP - 1 - fx] : N;
    }
    h8 v0 = *(const h8*)&Bm[(size_t)s[0] * FDIM + 8 * l];
    h8 v1 = *(const h8*)&Bm[(size_t)s[1] * FDIM + 8 * l];
    h8 v2 = *(const h8*)&Bm[(size_t)s[2] * FDIM + 8 * l];
    h8 v3 = *(const h8*)&Bm[(size_t)s[3] * FDIM + 8 * l];
    h8 u0 = *(const h8*)&Bm[(size_t)tt[0] * FDIM + 8 * l];
    h8 u1 = *(const h8*)&Bm[(size_t)tt[1] * FDIM + 8 * l];
    h8 u2 = *(const h8*)&Bm[(size_t)tt[2] * FDIM + 8 * l];
    h8 u3 = *(const h8*)&Bm[(size_t)tt[3] * FDIM + 8 * l];
#pragma unroll
    for (int q = 0; q < 8; ++q) {
      A[q] += ((float)v0[q] + (float)v1[q]) + ((float)v2[q] + (float)v3[q])
            + ((float)u0[q] + (float)u1[q]) + ((float)u2[q] + (float)u3[q]);
    }
  }
  float inv_i = 1.f / sqrtf(fmaxf((float)fi, 1.f));
  float4 o0, o1;
  o0.x = A[0] * inv_i; o0.y = A[1] * inv_i; o0.z = A[2] * inv_i; o0.w = A[3] * inv_i;
  o1.x = A[4] * inv_i; o1.y = A[5] * inv_i; o1.z = A[6] * inv_i; o1.w = A[7] * inv_i;
  *(float4*)&bufA[(size_t)n * FDIM + 8 * l] = o0;
  *(float4*)&bufA[(size_t)n * FDIM + 8 * l + 4] = o1;
}

// ---------------- pool + combine ----------------
__global__ __launch_bounds__(256) void pool_final(const float* __restrict__ feat,
    const float* __restrict__ u, const int* __restrict__ gid,
    const float* __restrict__ cvec, const float* __restrict__ bc,
    float* __restrict__ out, int N, int G) {
  __shared__ int sb[2];
  __shared__ float red[4][64];
  int g = blockIdx.x;
  int t = threadIdx.x;
  int rg = t >> 6, j = t & 63;
  if (t < 2) {
    int target = g + t;
    int lo = 0, hi = N;
    while (lo < hi) {
      int mid = (lo + hi) >> 1;
      if (gid[mid] < target) lo = mid + 1; else hi = mid;
    }
    sb[t] = lo;
  }
  __syncthreads();
  int beg = sb[0], end = sb[1];
  float acc = 0.f;
  for (int r = beg + rg; r < end; r += 4) {
    float v;
    if (j < NCLS + 1) v = feat[(size_t)r * FDIM + j];
    else if (j == NCLS + 1) v = u[r];
    else v = 0.f;
    acc += v;
  }
  red[rg][j] = acc;
  __syncthreads();
  if (rg == 0) {
    float s = red[0][j] + red[1][j] + red[2][j] + red[3][j];
    float cnt = (float)(end - beg);
    float inv = 1.f / fmaxf(cnt, 1.f);
    red[1][j] = s * inv;
  }
  __syncthreads();
  if (rg == 0 && j < NCLS) {
    float vbar = red[1][NCLS];
    float ubar = red[1][NCLS + 1];
    float ind = (end > beg) ? 1.f : 0.f;
    out[g * NCLS + j] = red[1][j] + vbar * cvec[j] + ubar * cvec[64 + j]
                        + ind * cvec[128 + j] + bc[j];
  }
}

extern "C" void kernel_launch(void* const* d_in, const int* in_sizes, int n_in,
                              void* d_out, int out_size, void* d_ws, size_t ws_size,
                              hipStream_t stream) {
  const float* X     = (const float*)d_in[0];
  const int*   src   = (const int*)d_in[1];
  const int*   dst   = (const int*)d_in[2];
  const int*   gid   = (const int*)d_in[3];
  const float* W_ext = (const float*)d_in[4];
  const float* b_ext = (const float*)d_in[5];
  const float* W1    = (const float*)d_in[6];
  const float* b1    = (const float*)d_in[7];
  const float* W2    = (const float*)d_in[8];
  const float* b2    = (const float*)d_in[9];
  const float* Wc    = (const float*)d_in[10];
  const float* bc    = (const float*)d_in[11];
  float* out = (float*)d_out;

  int N = in_sizes[0] / RAW;
  int E = in_sizes[1];
  int G = out_size / NCLS;

  char* p = (char*)d_ws;
  auto alloc = [&](size_t b) { char* r = p; p += (b + 255) & ~(size_t)255; return r; };

  int*            deg_o   = (int*)alloc((size_t)(N + 1) * 4);  // +1: dummy index N -> deg 0
  int*            fill_lo = (int*)alloc((size_t)N * 4);
  int*            fill_hi = (int*)alloc((size_t)N * 4);
  size_t zero_span = (size_t)(p - (char*)deg_o);
  unsigned short* csr_pad = (unsigned short*)alloc((size_t)N * CAP * 2);
  float*          P       = (float*)alloc((size_t)RAW * LAT * 4);
  float*          Qp      = (float*)alloc((size_t)LAT * 64 * 4);
  float*          rvec    = (float*)alloc((size_t)LAT * 4);
  float*          Wallp   = (float*)alloc((size_t)RAW * 64 * 4);
  float*          cvec    = (float*)alloc(192 * 4);
  float*          u_arr   = (float*)alloc((size_t)N * 4);
  _Float16*       Y       = (_Float16*)alloc((size_t)(N + 1) * FDIM * 2);  // +1 dummy zero row
  _Float16*       B       = (_Float16*)alloc((size_t)(N + 1) * FDIM * 2);
  float*          bufA    = (float*)alloc((size_t)N * FDIM * 4);

  int zcount16 = (int)(zero_span / 16);
  int nZ = (zcount16 + 255) / 256;

  // 6 dispatches total (was 12): s1, s2, mega, agg1, agg2, pool
  s1_kernel<<<nZ + 128 + 26 + 1, 256, 0, stream>>>(
      (int4*)deg_o, zcount16, Y + (size_t)N * FDIM, B + (size_t)N * FDIM,
      W_ext, W1, b_ext, W2, b2, Wc, P, Qp, rvec, cvec, nZ);

  s2_kernel<<<(RAW + 2 + 3) / 4, 256, 0, stream>>>(P, Qp, rvec, b1, Wallp, cvec);

  int nE = (E + 255) / 256;
  int nGm = (N + GR - 1) / GR;
  mega<<<nE + nGm, 256, 0, stream>>>(src, dst, deg_o, fill_lo, fill_hi, csr_pad, E,
                                     X, Wallp, Y, N, nE, nGm);

  int aggGrid = (N + 31) / 32;
  agg1_kernel<<<aggGrid, 256, 0, stream>>>(Y, csr_pad, fill_lo, fill_hi, deg_o, B, u_arr, N);
  agg2_kernel<<<aggGrid, 256, 0, stream>>>(B, csr_pad, fill_lo, fill_hi, bufA, N);

  pool_final<<<G, 256, 0, stream>>>(bufA, u_arr, gid, cvec, bc, out, N, G);
}

// Round 13
// 254.126 us; speedup vs baseline: 1.0178x; 1.0178x over previous
//
#include <hip/hip_runtime.h>

#define RAW 256
#define LAT 100
#define LAT2 200
#define NCLS 55
#define FDIM 64    // padded row: 0..54 classes, 55 ones-col, 56..63 zero (fp16 row = 128 B)
#define GR 32      // rows per gemm block (fp32 LDS tile = 32 KB; r4/r8/r9/r11/r12 ~100 us)
#define CAP 64     // per-array slot capacity (two buckets per array, filled from both ends)

typedef _Float16 h8 __attribute__((ext_vector_type(8)));

// ---- wave-per-row small-GEMM helpers (lane j = output col, 64-wide padded B) ----
__device__ __forceinline__ float dotrow(const float* __restrict__ Arow,
                                        const float* __restrict__ Bp, int K, int j) {
  float a0 = 0.f, a1 = 0.f, a2 = 0.f, a3 = 0.f;
  int k = 0;
  for (; k + 3 < K; k += 4) {
    a0 += Arow[k + 0] * Bp[(k + 0) * 64 + j];
    a1 += Arow[k + 1] * Bp[(k + 1) * 64 + j];
    a2 += Arow[k + 2] * Bp[(k + 2) * 64 + j];
    a3 += Arow[k + 3] * Bp[(k + 3) * 64 + j];
  }
  for (; k < K; ++k) a0 += Arow[k] * Bp[k * 64 + j];
  return (a0 + a1) + (a2 + a3);
}

__device__ __forceinline__ float dotrow_wc(const float* __restrict__ Arow,
                                           const float* __restrict__ Wc, int K, int j) {
  if (j >= NCLS) return 0.f;
  float a0 = 0.f, a1 = 0.f, a2 = 0.f, a3 = 0.f;
  for (int k = 0; k + 3 < K; k += 4) {
    a0 += Arow[k + 0] * Wc[(k + 0) * NCLS + j];
    a1 += Arow[k + 1] * Wc[(k + 1) * NCLS + j];
    a2 += Arow[k + 2] * Wc[(k + 2) * NCLS + j];
    a3 += Arow[k + 3] * Wc[(k + 3) * NCLS + j];
  }
  return (a0 + a1) + (a2 + a3);
}

// ---------------- s1: [zero counters][P = W_ext@W1][Qp = W2@Wc, c0][r = b_ext@W1] ----------------
__global__ __launch_bounds__(256) void s1_kernel(
    int4* __restrict__ zbase, int zcount16,
    const float* __restrict__ W_ext, const float* __restrict__ W1,
    const float* __restrict__ b_ext,
    const float* __restrict__ W2, const float* __restrict__ b2,
    const float* __restrict__ Wc,
    float* __restrict__ P, float* __restrict__ Qp,
    float* __restrict__ rvec, float* __restrict__ cvec, int nZ) {
  int b = blockIdx.x, t = threadIdx.x;
  if (b < nZ) {
    int idx = b * 256 + t;
    if (idx < zcount16) zbase[idx] = make_int4(0, 0, 0, 0);
    return;
  }
  b -= nZ;
  if (b < 128) {  // P rows: 2 rows/block, 128 lanes/row
    int row = b * 2 + (t >> 7);
    int col = t & 127;
    if (col < LAT) {
      const float* a = &W_ext[row * LAT];
      float s0 = 0.f, s1 = 0.f, s2 = 0.f, s3 = 0.f;
      for (int k = 0; k < LAT; k += 4) {
        s0 += a[k + 0] * W1[(k + 0) * LAT + col];
        s1 += a[k + 1] * W1[(k + 1) * LAT + col];
        s2 += a[k + 2] * W1[(k + 2) * LAT + col];
        s3 += a[k + 3] * W1[(k + 3) * LAT + col];
      }
      P[row * LAT + col] = (s0 + s1) + (s2 + s3);
    }
    return;
  }
  b -= 128;
  if (b < 26) {  // Q rows + c0
    int task = b * 4 + (t >> 6);
    int j = t & 63;
    if (task < LAT)
      Qp[task * 64 + j] = dotrow_wc(&W2[task * LAT2], Wc, LAT2, j);
    else if (task == LAT)
      cvec[128 + j] = dotrow_wc(b2, Wc, LAT2, j);  // c0
    return;
  }
  // r = b_ext @ W1
  if (t < LAT) {
    float s0 = 0.f, s1 = 0.f, s2 = 0.f, s3 = 0.f;
    for (int k = 0; k < LAT; k += 4) {
      s0 += b_ext[k + 0] * W1[(k + 0) * LAT + t];
      s1 += b_ext[k + 1] * W1[(k + 1) * LAT + t];
      s2 += b_ext[k + 2] * W1[(k + 2) * LAT + t];
      s3 += b_ext[k + 3] * W1[(k + 3) * LAT + t];
    }
    rvec[t] = (s0 + s1) + (s2 + s3);
  }
}

// ---------------- s2: Wall = P@Qp, c2 = r@Qp, c1 = b1@Qp ----------------
__global__ __launch_bounds__(256) void s2_kernel(
    const float* __restrict__ P, const float* __restrict__ Qp,
    const float* __restrict__ rvec, const float* __restrict__ b1,
    float* __restrict__ Wallp, float* __restrict__ cvec) {
  int task = blockIdx.x * 4 + (threadIdx.x >> 6);
  int j = threadIdx.x & 63;
  if (task < RAW)
    Wallp[task * 64 + j] = dotrow(&P[task * LAT], Qp, LAT, j);
  else if (task == RAW)
    cvec[j] = dotrow(rvec, Qp, LAT, j);       // c2
  else if (task == RAW + 1)
    cvec[64 + j] = dotrow(b1, Qp, LAT, j);    // c1
}

// ---------------- mega: edge blocks (4-bucket split-cursor CSR + out-deg atomics) ∥ gemm blocks ----
// Bucket by source quartile: csrA front = [0,N/4), csrA back = [N/4,N/2),
//                            csrB front = [N/2,3N/4), csrB back = [3N/4,N).
__global__ __launch_bounds__(256) void mega(
    const int* __restrict__ src, const int* __restrict__ dst,
    int* deg_o, int* fA_lo, int* fA_hi, int* fB_lo, int* fB_hi,
    unsigned short* csrA, unsigned short* csrB, int E,
    const float* __restrict__ X, const float* __restrict__ Wallp,
    _Float16* __restrict__ Y, int N, int nE, int nGm) {
  __shared__ float Xs[GR][RAW];  // 32 KB
  int b = blockIdx.x;
  int t = threadIdx.x;
  int total = nE + nGm;
  long long lo = (long long)b * nGm / total;
  long long hi = (long long)(b + 1) * nGm / total;
  if (hi == lo) {
    // ---- edge block ----
    int e = (b - (int)lo) * 256 + t;
    if (e < E) {
      int s = src[e];
      int d = dst[e];
      int q1 = N >> 2, q2 = N >> 1, q3 = q1 + q2;
      unsigned short us = (unsigned short)s;
      if (s < q2) {
        if (s < q1) {
          int cur = atomicAdd(&fA_lo[d], 1);
          if (cur < CAP) csrA[(size_t)d * CAP + cur] = us;
        } else {
          int cur = atomicAdd(&fA_hi[d], 1);
          int pos = CAP - 1 - cur;
          if (pos >= 0) csrA[(size_t)d * CAP + pos] = us;
        }
      } else {
        if (s < q3) {
          int cur = atomicAdd(&fB_lo[d], 1);
          if (cur < CAP) csrB[(size_t)d * CAP + cur] = us;
        } else {
          int cur = atomicAdd(&fB_hi[d], 1);
          int pos = CAP - 1 - cur;
          if (pos >= 0) csrB[(size_t)d * CAP + pos] = us;
        }
      }
      atomicAdd(&deg_o[s], 1);
    }
    return;
  }
  // ---- gemm block ----
  int r0 = (int)lo * GR;
#pragma unroll
  for (int i = 0; i < 8; ++i) {
    int f = t + 256 * i;
    int rr = f >> 6;
    int kp = (f & 63) << 2;
    int row = r0 + rr;
    float4 v = make_float4(0.f, 0.f, 0.f, 0.f);
    if (row < N) v = *(const float4*)&X[(size_t)row * RAW + kp];
    *(float4*)&Xs[rr][kp] = v;
  }
  __syncthreads();
  int j = t & 63;
  int rg = t >> 6;
  float acc[8];
#pragma unroll
  for (int i = 0; i < 8; ++i) acc[i] = 0.f;
  for (int k = 0; k < RAW; k += 4) {
    float w0 = Wallp[(k + 0) * 64 + j];
    float w1 = Wallp[(k + 1) * 64 + j];
    float w2 = Wallp[(k + 2) * 64 + j];
    float w3 = Wallp[(k + 3) * 64 + j];
#pragma unroll
    for (int i = 0; i < 8; ++i) {
      float4 x = *(const float4*)&Xs[rg * 8 + i][k];
      acc[i] += x.x * w0 + x.y * w1 + x.z * w2 + x.w * w3;
    }
  }
#pragma unroll
  for (int i = 0; i < 8; ++i) {
    int row = r0 + rg * 8 + i;
    if (row < N) {
      float val = (j < NCLS) ? acc[i] : ((j == NCLS) ? 1.f : 0.f);
      Y[(size_t)row * FDIM + j] = (_Float16)val;
    }
  }
}

// ---------------- scaleY: Y[n] *= inv_o(n)  (col 55: 1 -> inv_o) ----------------
__global__ __launch_bounds__(256) void scaleY(_Float16* __restrict__ Y,
                                              const int* __restrict__ deg_o, int N) {
  int idx = blockIdx.x * 256 + threadIdx.x;  // one h8 (16 B) per thread
  int n = idx >> 3;
  int c = (idx & 7) * 8;
  if (n >= N) return;
  float w = 1.f / sqrtf(fmaxf((float)deg_o[n], 1.f));
  h8 v = *(h8*)&Y[(size_t)n * FDIM + c];
#pragma unroll
  for (int q = 0; q < 8; ++q) v[q] = (_Float16)((float)v[q] * w);
  *(h8*)&Y[(size_t)n * FDIM + c] = v;
}

// ---- one gather sweep over lst[beg,end): rows are confined to one source quartile ----
__device__ __forceinline__ void sweep(const _Float16* __restrict__ SRC,
    const unsigned short* __restrict__ lst, int beg, int end, int l,
    float* __restrict__ A0, float* __restrict__ A1) {
  int i = beg;
  for (; i + 3 < end; i += 4) {
    int s0 = lst[i], s1 = lst[i + 1], s2 = lst[i + 2], s3 = lst[i + 3];
    h8 v0 = *(const h8*)&SRC[(size_t)s0 * FDIM + 8 * l];
    h8 v1 = *(const h8*)&SRC[(size_t)s1 * FDIM + 8 * l];
    h8 v2 = *(const h8*)&SRC[(size_t)s2 * FDIM + 8 * l];
    h8 v3 = *(const h8*)&SRC[(size_t)s3 * FDIM + 8 * l];
#pragma unroll
    for (int q = 0; q < 8; ++q) {
      A0[q] += (float)v0[q] + (float)v2[q];
      A1[q] += (float)v1[q] + (float)v3[q];
    }
  }
  for (; i < end; ++i) {
    h8 v = *(const h8*)&SRC[(size_t)lst[i] * FDIM + 8 * l];
#pragma unroll
    for (int q = 0; q < 8; ++q) A0[q] += (float)v[q];
  }
}

// ---------------- agg1: 4-sweep gather (1.6 MB hot set each); B = s_mid(n)·Σ Y[s] ----------------
__global__ __launch_bounds__(256) void agg1_kernel(const _Float16* __restrict__ Y,
    const unsigned short* __restrict__ csrA, const unsigned short* __restrict__ csrB,
    const int* __restrict__ fA_lo, const int* __restrict__ fA_hi,
    const int* __restrict__ fB_lo, const int* __restrict__ fB_hi,
    const int* __restrict__ deg_o,
    _Float16* __restrict__ B, float* __restrict__ u_out, int N) {
  int n = blockIdx.x * 32 + (threadIdx.x >> 3);
  int l = threadIdx.x & 7;
  if (n >= N) return;
  int al = min(fA_lo[n], CAP), ah = min(fA_hi[n], CAP);
  int bl = min(fB_lo[n], CAP), bh = min(fB_hi[n], CAP);
  int fi = fA_lo[n] + fA_hi[n] + fB_lo[n] + fB_hi[n];
  const unsigned short* lA = &csrA[(size_t)n * CAP];
  const unsigned short* lB = &csrB[(size_t)n * CAP];
  float A0[8], A1[8];
#pragma unroll
  for (int q = 0; q < 8; ++q) { A0[q] = 0.f; A1[q] = 0.f; }
  sweep(Y, lA, 0, al, l, A0, A1);            // quartile 0
  sweep(Y, lA, CAP - ah, CAP, l, A0, A1);    // quartile 1
  sweep(Y, lB, 0, bl, l, A0, A1);            // quartile 2
  sweep(Y, lB, CAP - bh, CAP, l, A0, A1);    // quartile 3
  float inv_i = 1.f / sqrtf(fmaxf((float)fi, 1.f));
  float inv_on = 1.f / sqrtf(fmaxf((float)deg_o[n], 1.f));
  float sm = inv_i * inv_on;                 // next layer's inv_o pre-applied
  h8 o;
#pragma unroll
  for (int q = 0; q < 8; ++q) o[q] = (_Float16)((A0[q] + A1[q]) * sm);
  *(h8*)&B[(size_t)n * FDIM + 8 * l] = o;
  if (l == 6) u_out[n] = (A0[7] + A1[7]) * inv_i;  // col 55
}

// ---------------- agg2: 4-sweep gather; bufA fp32 = inv_i(n)·Σ B[s] ----------------
__global__ __launch_bounds__(256) void agg2_kernel(const _Float16* __restrict__ Bm,
    const unsigned short* __restrict__ csrA, const unsigned short* __restrict__ csrB,
    const int* __restrict__ fA_lo, const int* __restrict__ fA_hi,
    const int* __restrict__ fB_lo, const int* __restrict__ fB_hi,
    float* __restrict__ bufA, int N) {
  int n = blockIdx.x * 32 + (threadIdx.x >> 3);
  int l = threadIdx.x & 7;
  if (n >= N) return;
  int al = min(fA_lo[n], CAP), ah = min(fA_hi[n], CAP);
  int bl = min(fB_lo[n], CAP), bh = min(fB_hi[n], CAP);
  int fi = fA_lo[n] + fA_hi[n] + fB_lo[n] + fB_hi[n];
  const unsigned short* lA = &csrA[(size_t)n * CAP];
  const unsigned short* lB = &csrB[(size_t)n * CAP];
  float A0[8], A1[8];
#pragma unroll
  for (int q = 0; q < 8; ++q) { A0[q] = 0.f; A1[q] = 0.f; }
  sweep(Bm, lA, 0, al, l, A0, A1);
  sweep(Bm, lA, CAP - ah, CAP, l, A0, A1);
  sweep(Bm, lB, 0, bl, l, A0, A1);
  sweep(Bm, lB, CAP - bh, CAP, l, A0, A1);
  float inv_i = 1.f / sqrtf(fmaxf((float)fi, 1.f));
  float4 o0, o1;
  o0.x = (A0[0] + A1[0]) * inv_i; o0.y = (A0[1] + A1[1]) * inv_i;
  o0.z = (A0[2] + A1[2]) * inv_i; o0.w = (A0[3] + A1[3]) * inv_i;
  o1.x = (A0[4] + A1[4]) * inv_i; o1.y = (A0[5] + A1[5]) * inv_i;
  o1.z = (A0[6] + A1[6]) * inv_i; o1.w = (A0[7] + A1[7]) * inv_i;
  *(float4*)&bufA[(size_t)n * FDIM + 8 * l] = o0;
  *(float4*)&bufA[(size_t)n * FDIM + 8 * l + 4] = o1;
}

// ---------------- pool + combine ----------------
__global__ __launch_bounds__(256) void pool_final(const float* __restrict__ feat,
    const float* __restrict__ u, const int* __restrict__ gid,
    const float* __restrict__ cvec, const float* __restrict__ bc,
    float* __restrict__ out, int N, int G) {
  __shared__ int sb[2];
  __shared__ float red[4][64];
  int g = blockIdx.x;
  int t = threadIdx.x;
  int rg = t >> 6, j = t & 63;
  if (t < 2) {
    int target = g + t;
    int lo = 0, hi = N;
    while (lo < hi) {
      int mid = (lo + hi) >> 1;
      if (gid[mid] < target) lo = mid + 1; else hi = mid;
    }
    sb[t] = lo;
  }
  __syncthreads();
  int beg = sb[0], end = sb[1];
  float acc = 0.f;
  for (int r = beg + rg; r < end; r += 4) {
    float v;
    if (j < NCLS + 1) v = feat[(size_t)r * FDIM + j];
    else if (j == NCLS + 1) v = u[r];
    else v = 0.f;
    acc += v;
  }
  red[rg][j] = acc;
  __syncthreads();
  if (rg == 0) {
    float s = red[0][j] + red[1][j] + red[2][j] + red[3][j];
    float cnt = (float)(end - beg);
    float inv = 1.f / fmaxf(cnt, 1.f);
    red[1][j] = s * inv;
  }
  __syncthreads();
  if (rg == 0 && j < NCLS) {
    float vbar = red[1][NCLS];
    float ubar = red[1][NCLS + 1];
    float ind = (end > beg) ? 1.f : 0.f;
    out[g * NCLS + j] = red[1][j] + vbar * cvec[j] + ubar * cvec[64 + j]
                        + ind * cvec[128 + j] + bc[j];
  }
}

extern "C" void kernel_launch(void* const* d_in, const int* in_sizes, int n_in,
                              void* d_out, int out_size, void* d_ws, size_t ws_size,
                              hipStream_t stream) {
  const float* X     = (const float*)d_in[0];
  const int*   src   = (const int*)d_in[1];
  const int*   dst   = (const int*)d_in[2];
  const int*   gid   = (const int*)d_in[3];
  const float* W_ext = (const float*)d_in[4];
  const float* b_ext = (const float*)d_in[5];
  const float* W1    = (const float*)d_in[6];
  const float* b1    = (const float*)d_in[7];
  const float* W2    = (const float*)d_in[8];
  const float* b2    = (const float*)d_in[9];
  const float* Wc    = (const float*)d_in[10];
  const float* bc    = (const float*)d_in[11];
  float* out = (float*)d_out;

  int N = in_sizes[0] / RAW;
  int E = in_sizes[1];
  int G = out_size / NCLS;

  char* p = (char*)d_ws;
  auto alloc = [&](size_t b) { char* r = p; p += (b + 255) & ~(size_t)255; return r; };

  int*            deg_o   = (int*)alloc((size_t)N * 4);
  int*            fA_lo   = (int*)alloc((size_t)N * 4);
  int*            fA_hi   = (int*)alloc((size_t)N * 4);
  int*            fB_lo   = (int*)alloc((size_t)N * 4);
  int*            fB_hi   = (int*)alloc((size_t)N * 4);
  size_t zero_span = (size_t)(p - (char*)deg_o);
  unsigned short* csrA    = (unsigned short*)alloc((size_t)N * CAP * 2);
  unsigned short* csrB    = (unsigned short*)alloc((size_t)N * CAP * 2);
  float*          P       = (float*)alloc((size_t)RAW * LAT * 4);
  float*          Qp      = (float*)alloc((size_t)LAT * 64 * 4);
  float*          rvec    = (float*)alloc((size_t)LAT * 4);
  float*          Wallp   = (float*)alloc((size_t)RAW * 64 * 4);
  float*          cvec    = (float*)alloc(192 * 4);
  float*          u_arr   = (float*)alloc((size_t)N * 4);
  _Float16*       Y       = (_Float16*)alloc((size_t)N * FDIM * 2);
  _Float16*       B       = (_Float16*)alloc((size_t)N * FDIM * 2);
  float*          bufA    = (float*)alloc((size_t)N * FDIM * 4);

  int zcount16 = (int)(zero_span / 16);
  int nZ = (zcount16 + 255) / 256;

  s1_kernel<<<nZ + 128 + 26 + 1, 256, 0, stream>>>(
      (int4*)deg_o, zcount16, W_ext, W1, b_ext, W2, b2, Wc, P, Qp, rvec, cvec, nZ);

  s2_kernel<<<(RAW + 2 + 3) / 4, 256, 0, stream>>>(P, Qp, rvec, b1, Wallp, cvec);

  int nE = (E + 255) / 256;
  int nGm = (N + GR - 1) / GR;
  mega<<<nE + nGm, 256, 0, stream>>>(src, dst, deg_o, fA_lo, fA_hi, fB_lo, fB_hi,
                                     csrA, csrB, E, X, Wallp, Y, N, nE, nGm);

  scaleY<<<(N * 8 + 255) / 256, 256, 0, stream>>>(Y, deg_o, N);

  int aggGrid = (N + 31) / 32;
  agg1_kernel<<<aggGrid, 256, 0, stream>>>(Y, csrA, csrB, fA_lo, fA_hi, fB_lo, fB_hi,
                                           deg_o, B, u_arr, N);
  agg2_kernel<<<aggGrid, 256, 0, stream>>>(B, csrA, csrB, fA_lo, fA_hi, fB_lo, fB_hi,
                                           bufA, N);

  pool_final<<<G, 256, 0, stream>>>(bufA, u_arr, gid, cvec, bc, out, N, G);
}